// Round 4
// baseline (299.588 us; speedup 1.0000x reference)
//
#include <hip/hip_runtime.h>

// RFCM loss, fused single pass + finalize. B=2, K=4, D=H=W=128. Scalar out.
//
// mean(J1) = (1/(B*N)) * sum_{b,k} [ A_bk - Sim_bk^2 / Sm_bk ]
//   Sm=sum mem, Sim=sum mem*img, A=sum mem*img^2, mem=y_pred^2
// mean(J2) = (1/(B*N)) * sum_n [ Sm*Sbk - Sm^2 - sum_k m*bk + sum_k m^2 ]
//   bk = box27(mem_k) incl center, zero pad.
//
// R4: latency attack. (1) w-halo via __shfl of vertical sums: 13 VMEM/step
// instead of 37. (2) SD=4 -> 2048 blocks, launch_bounds(128,4) -> 16
// waves/CU. (3) XCD swizzle: all 32 h-tiles of one (b,dsb) slab (1.5 MB
// working set) on one XCD's L2.

#define BB 2
#define KK 4
#define DD 128
#define HH 128
#define WW 128
#define PLANE (HH * WW)
#define SD 4
#define NBD (DD / SD)   // 32
#define HR 4            // rows per block
#define NBH (HH / HR)   // 32
#define NT 128          // 32 w-lanes x 4 rows

__global__ __launch_bounds__(NT, 4) void rfcm_main(
    const float* __restrict__ yp, const float* __restrict__ img,
    double* __restrict__ ws)
{
    const int tid = threadIdx.x;
    const int wl  = tid & 31;       // w-lane: owns cols c0..c0+3
    const int hr  = tid >> 5;       // 0..3: own row
    const int c0  = wl << 2;

    // XCD swizzle: bid -> (group, m) with group = (gi<<3)|xcd so that all 32
    // ht-members of a (b,dsb) group share one XCD's L2 (round-robin %8 map).
    const int bid = blockIdx.x;
    const int xcd = bid & 7;
    const int s   = bid >> 3;          // 0..255
    const int gi  = s >> 5;            // 0..7
    const int ht  = s & 31;            // h-tile
    const int grp = (gi << 3) | xcd;   // 0..63
    const int b   = grp >> 5;
    const int dsb = grp & 31;

    const int h   = ht * HR + hr;
    const int d0  = dsb * SD;

    const bool okL = (wl > 0), okR = (wl < 31);
    const float msc = (h > 0)      ? 1.f : 0.f;
    const float psc = (h < HH - 1) ? 1.f : 0.f;
    const int hm = (h > 0)      ? h - 1 : h;
    const int hp = (h < HH - 1) ? h + 1 : h;

    const float* base = yp + (size_t)b * KK * DD * PLANE;
    const int offM = hm * WW + c0;
    const int off0 = h  * WW + c0;
    const int offP = hp * WW + c0;

    // hw9 3x3 (h,w) box sums of mem + center squares m for plane t, all k
    auto stepload = [&](int t, float4 (&s9)[KK], float4 (&mm)[KK]) {
        if ((unsigned)t < (unsigned)DD) {
            #pragma unroll
            for (int k = 0; k < KK; k++) {
                const float* pt = base + ((size_t)k * DD + t) * PLANE;
                const float4 a4 = *(const float4*)(pt + offM);
                const float4 b4 = *(const float4*)(pt + off0);
                const float4 c4 = *(const float4*)(pt + offP);

                float4 sb = make_float4(b4.x*b4.x, b4.y*b4.y, b4.z*b4.z, b4.w*b4.w);
                mm[k] = sb;

                float4 v;   // vertical 3-sum of squares, own 4 cols
                v.x = fmaf(a4.x*a4.x, msc, fmaf(c4.x*c4.x, psc, sb.x));
                v.y = fmaf(a4.y*a4.y, msc, fmaf(c4.y*c4.y, psc, sb.y));
                v.z = fmaf(a4.z*a4.z, msc, fmaf(c4.z*c4.z, psc, sb.z));
                v.w = fmaf(a4.w*a4.w, msc, fmaf(c4.w*c4.w, psc, sb.w));

                // w-halo via cross-lane: lane wl-1's v.w, lane wl+1's v.x.
                // Row groups are 32 lanes; the wl==0/31 wrap crosses rows but
                // is masked to 0 (w boundary) anyway.
                const float vL = okL ? __shfl_up(v.w, 1)   : 0.f;
                const float vR = okR ? __shfl_down(v.x, 1) : 0.f;

                s9[k].x = vL  + v.x + v.y;
                s9[k].y = v.x + v.y + v.z;
                s9[k].z = v.y + v.z + v.w;
                s9[k].w = v.z + v.w + vR;
            }
        } else {
            #pragma unroll
            for (int k = 0; k < KK; k++) {
                s9[k] = make_float4(0.f, 0.f, 0.f, 0.f);
                mm[k] = make_float4(0.f, 0.f, 0.f, 0.f);
            }
        }
    };

    float4 s9p[KK], s9c[KK], s9n[KK], mc[KK], mn[KK];
    stepload(d0 - 1, s9p, mn);   // mn is scratch here
    stepload(d0,     s9c, mc);

    float smf[KK] = {0,0,0,0}, sif[KK] = {0,0,0,0}, saf[KK] = {0,0,0,0};
    float j2f = 0.f;

    const float* imgb = img + (size_t)b * DD * PLANE + off0;

    #pragma unroll
    for (int i = 0; i < SD; i++) {
        const int d = d0 + i;
        stepload(d + 1, s9n, mn);

        const float4 iv = *(const float4*)(imgb + (size_t)d * PLANE);
        const float4 iv2 = make_float4(iv.x*iv.x, iv.y*iv.y, iv.z*iv.z, iv.w*iv.w);

        float4 summ  = make_float4(0.f, 0.f, 0.f, 0.f);
        float4 sumbk = make_float4(0.f, 0.f, 0.f, 0.f);
        float4 cross = make_float4(0.f, 0.f, 0.f, 0.f);

        #pragma unroll
        for (int k = 0; k < KK; k++) {
            const float4 m = mc[k];
            float4 bk;
            bk.x = s9p[k].x + s9c[k].x + s9n[k].x;
            bk.y = s9p[k].y + s9c[k].y + s9n[k].y;
            bk.z = s9p[k].z + s9c[k].z + s9n[k].z;
            bk.w = s9p[k].w + s9c[k].w + s9n[k].w;

            summ.x += m.x; summ.y += m.y; summ.z += m.z; summ.w += m.w;
            sumbk.x += bk.x; sumbk.y += bk.y; sumbk.z += bk.z; sumbk.w += bk.w;
            cross.x = fmaf(m.x, bk.x - m.x, cross.x);
            cross.y = fmaf(m.y, bk.y - m.y, cross.y);
            cross.z = fmaf(m.z, bk.z - m.z, cross.z);
            cross.w = fmaf(m.w, bk.w - m.w, cross.w);

            smf[k] += (m.x + m.y) + (m.z + m.w);
            sif[k] = fmaf(m.x, iv.x,  fmaf(m.y, iv.y,  fmaf(m.z, iv.z,  fmaf(m.w, iv.w,  sif[k]))));
            saf[k] = fmaf(m.x, iv2.x, fmaf(m.y, iv2.y, fmaf(m.z, iv2.z, fmaf(m.w, iv2.w, saf[k]))));

            s9p[k] = s9c[k]; s9c[k] = s9n[k]; mc[k] = mn[k];
        }

        j2f += (summ.x * (sumbk.x - summ.x) - cross.x)
             + (summ.y * (sumbk.y - summ.y) - cross.y)
             + (summ.z * (sumbk.z - summ.z) - cross.z)
             + (summ.w * (sumbk.w - summ.w) - cross.w);
    }

    // ---- block reduction of 13 scalars ----
    double q[13];
    #pragma unroll
    for (int k = 0; k < KK; k++) {
        q[k] = (double)smf[k]; q[4 + k] = (double)sif[k]; q[8 + k] = (double)saf[k];
    }
    q[12] = (double)j2f;

    #pragma unroll
    for (int qq = 0; qq < 13; qq++) {
        double v = q[qq];
        #pragma unroll
        for (int off = 32; off > 0; off >>= 1) v += __shfl_down(v, off, 64);
        q[qq] = v;
    }

    __shared__ double red[2 * 13];
    const int lane = tid & 63, wid = tid >> 6;
    if (lane == 0) {
        #pragma unroll
        for (int qq = 0; qq < 13; qq++) red[wid * 13 + qq] = q[qq];
    }
    __syncthreads();
    if (tid < 13) {
        const double sfin = red[tid] + red[13 + tid];
        int idx;
        if      (tid < 4)  idx = b * KK + tid;              // Sm
        else if (tid < 8)  idx = 8  + b * KK + (tid - 4);   // Sim
        else if (tid < 12) idx = 16 + b * KK + (tid - 8);   // A
        else               idx = 24;                        // J2
        unsafeAtomicAdd(&ws[idx], sfin);
    }
}

__global__ void rfcm_fin(const double* __restrict__ ws, float* __restrict__ out)
{
    if (threadIdx.x == 0 && blockIdx.x == 0) {
        double j1 = 0;
        #pragma unroll
        for (int i = 0; i < BB * KK; i++)
            j1 += ws[16 + i] - ws[8 + i] * ws[8 + i] / ws[i];
        const double invBN = 1.0 / ((double)BB * (double)DD * (double)HH * (double)WW);
        out[0] = (float)(j1 * invBN + 0.0008 * ws[24] * invBN);
    }
}

extern "C" void kernel_launch(void* const* d_in, const int* in_sizes, int n_in,
                              void* d_out, int out_size, void* d_ws, size_t ws_size,
                              hipStream_t stream) {
    const float* yp  = (const float*)d_in[0];   // y_pred [2,4,128,128,128]
    const float* img = (const float*)d_in[1];   // image  [2,1,128,128,128]
    float* out = (float*)d_out;
    double* ws = (double*)d_ws;

    hipMemsetAsync(d_ws, 0, 25 * sizeof(double), stream);

    dim3 grid(BB * NBD * NBH);   // 2048 blocks
    rfcm_main<<<grid, NT, 0, stream>>>(yp, img, ws);
    rfcm_fin<<<1, 64, 0, stream>>>(ws, out);
}

// Round 5
// 151.589 us; speedup vs baseline: 1.9763x; 1.9763x over previous
//
#include <hip/hip_runtime.h>

// RFCM loss, fused single pass + finalize. B=2, K=4, D=H=W=128. Scalar out.
//
// mean(J1) = (1/(B*N)) * sum_{b,k} [ A_bk - Sim_bk^2 / Sm_bk ]
//   Sm=sum mem, Sim=sum mem*img, A=sum mem*img^2, mem=y_pred^2
// mean(J2) = (1/(B*N)) * sum_n [ Sm*Sbk - Sm^2 - sum_k m*bk + sum_k m^2 ]
//   bk = box27(mem_k) incl center, zero pad.
//
// R5: software-pipelined register prefetch. Raw rows Ra/Rb/Rc[k] are loaded
// one full iteration before their reduce (load->use ~480 VALU cy > L2 lat).
// Keep R4's shuffle w-halo (13 VMEM/step) + XCD swizzle + 2048 blocks.
// NO min-waves launch bound: R4's (128,4) forced VGPR=64 -> 326 MB scratch
// spill traffic (WRITE_SIZE counter) and a 3x regression.

#define BB 2
#define KK 4
#define DD 128
#define HH 128
#define WW 128
#define PLANE (HH * WW)
#define SD 4
#define NBD (DD / SD)   // 32
#define HR 4            // rows per block
#define NBH (HH / HR)   // 32
#define NT 128          // 32 w-lanes x 4 rows

__global__ __launch_bounds__(NT) void rfcm_main(
    const float* __restrict__ yp, const float* __restrict__ img,
    double* __restrict__ ws)
{
    const int tid = threadIdx.x;
    const int wl  = tid & 31;       // w-lane: owns cols c0..c0+3
    const int hr  = tid >> 5;       // 0..3: own row
    const int c0  = wl << 2;

    // XCD swizzle: 32 ht-tiles of one (b,dsb) slab share one XCD's L2.
    const int bid = blockIdx.x;
    const int xcd = bid & 7;
    const int s   = bid >> 3;          // 0..255
    const int gi  = s >> 5;            // 0..7
    const int ht  = s & 31;
    const int grp = (gi << 3) | xcd;   // 0..63
    const int b   = grp >> 5;
    const int dsb = grp & 31;

    const int h   = ht * HR + hr;
    const int d0  = dsb * SD;

    const bool okL = (wl > 0), okR = (wl < 31);
    const float msc = (h > 0)      ? 1.f : 0.f;
    const float psc = (h < HH - 1) ? 1.f : 0.f;
    const int hm = (h > 0)      ? h - 1 : h;
    const int hp = (h < HH - 1) ? h + 1 : h;

    const float* base = yp + (size_t)b * KK * DD * PLANE;
    const int offM = hm * WW + c0;
    const int off0 = h  * WW + c0;
    const int offP = hp * WW + c0;

    // raw row pipeline: plane currently in flight / pending reduce
    float4 Ra[KK], Rb[KK], Rc[KK];

    auto issueK = [&](int t, int k) {
        if ((unsigned)t < (unsigned)DD) {
            const float* pt = base + ((size_t)(k * DD + t)) * PLANE;
            Ra[k] = *(const float4*)(pt + offM);
            Rb[k] = *(const float4*)(pt + off0);
            Rc[k] = *(const float4*)(pt + offP);
        } else {
            Ra[k] = make_float4(0.f, 0.f, 0.f, 0.f);
            Rb[k] = make_float4(0.f, 0.f, 0.f, 0.f);
            Rc[k] = make_float4(0.f, 0.f, 0.f, 0.f);
        }
    };

    // reduce R[k] -> hw9 3x3 box sum (s9) + center squares (mm)
    auto reduceK = [&](int k, float4& s9, float4& mm) {
        float4 sb = make_float4(Rb[k].x * Rb[k].x, Rb[k].y * Rb[k].y,
                                Rb[k].z * Rb[k].z, Rb[k].w * Rb[k].w);
        mm = sb;
        float4 v;   // vertical 3-sum of squares on own 4 cols
        v.x = fmaf(Ra[k].x * Ra[k].x, msc, fmaf(Rc[k].x * Rc[k].x, psc, sb.x));
        v.y = fmaf(Ra[k].y * Ra[k].y, msc, fmaf(Rc[k].y * Rc[k].y, psc, sb.y));
        v.z = fmaf(Ra[k].z * Ra[k].z, msc, fmaf(Rc[k].z * Rc[k].z, psc, sb.z));
        v.w = fmaf(Ra[k].w * Ra[k].w, msc, fmaf(Rc[k].w * Rc[k].w, psc, sb.w));
        // w-halo via cross-lane (wrap rows masked to 0 at w boundary)
        const float vL = okL ? __shfl_up(v.w, 1)   : 0.f;
        const float vR = okR ? __shfl_down(v.x, 1) : 0.f;
        s9.x = vL  + v.x + v.y;
        s9.y = v.x + v.y + v.z;
        s9.z = v.y + v.z + v.w;
        s9.w = v.z + v.w + vR;
    };

    float4 s9p[KK], s9c[KK], mc[KK], dum;
    // prologue with interleaved issue/reduce to build pipeline distance
    #pragma unroll
    for (int k = 0; k < KK; k++) issueK(d0 - 1, k);
    #pragma unroll
    for (int k = 0; k < KK; k++) { reduceK(k, s9p[k], dum); issueK(d0, k); }
    #pragma unroll
    for (int k = 0; k < KK; k++) { reduceK(k, s9c[k], mc[k]); issueK(d0 + 1, k); }

    const float* imgb = img + (size_t)b * DD * PLANE + off0;
    float4 iv = *(const float4*)(imgb + (size_t)d0 * PLANE);

    float smf[KK] = {0,0,0,0}, sif[KK] = {0,0,0,0}, saf[KK] = {0,0,0,0};
    float j2f = 0.f;

    #pragma unroll
    for (int i = 0; i < SD; i++) {
        const int d = d0 + i;

        float4 ivn;
        if (i < SD - 1) ivn = *(const float4*)(imgb + (size_t)(d + 1) * PLANE);

        const float4 iv2 = make_float4(iv.x*iv.x, iv.y*iv.y, iv.z*iv.z, iv.w*iv.w);

        float4 summ  = make_float4(0.f, 0.f, 0.f, 0.f);
        float4 sumbk = make_float4(0.f, 0.f, 0.f, 0.f);
        float4 cross = make_float4(0.f, 0.f, 0.f, 0.f);

        #pragma unroll
        for (int k = 0; k < KK; k++) {
            float4 s9n, mn;
            reduceK(k, s9n, mn);          // consume plane d+1 (loaded last iter)
            if (i < SD - 1) issueK(d + 2, k);  // refill: consumed next iter

            const float4 m = mc[k];
            float4 bk;
            bk.x = s9p[k].x + s9c[k].x + s9n.x;
            bk.y = s9p[k].y + s9c[k].y + s9n.y;
            bk.z = s9p[k].z + s9c[k].z + s9n.z;
            bk.w = s9p[k].w + s9c[k].w + s9n.w;

            summ.x += m.x; summ.y += m.y; summ.z += m.z; summ.w += m.w;
            sumbk.x += bk.x; sumbk.y += bk.y; sumbk.z += bk.z; sumbk.w += bk.w;
            cross.x = fmaf(m.x, bk.x - m.x, cross.x);
            cross.y = fmaf(m.y, bk.y - m.y, cross.y);
            cross.z = fmaf(m.z, bk.z - m.z, cross.z);
            cross.w = fmaf(m.w, bk.w - m.w, cross.w);

            smf[k] += (m.x + m.y) + (m.z + m.w);
            sif[k] = fmaf(m.x, iv.x,  fmaf(m.y, iv.y,  fmaf(m.z, iv.z,  fmaf(m.w, iv.w,  sif[k]))));
            saf[k] = fmaf(m.x, iv2.x, fmaf(m.y, iv2.y, fmaf(m.z, iv2.z, fmaf(m.w, iv2.w, saf[k]))));

            s9p[k] = s9c[k]; s9c[k] = s9n; mc[k] = mn;
        }

        j2f += (summ.x * (sumbk.x - summ.x) - cross.x)
             + (summ.y * (sumbk.y - summ.y) - cross.y)
             + (summ.z * (sumbk.z - summ.z) - cross.z)
             + (summ.w * (sumbk.w - summ.w) - cross.w);

        if (i < SD - 1) iv = ivn;
    }

    // ---- block reduction of 13 scalars ----
    double q[13];
    #pragma unroll
    for (int k = 0; k < KK; k++) {
        q[k] = (double)smf[k]; q[4 + k] = (double)sif[k]; q[8 + k] = (double)saf[k];
    }
    q[12] = (double)j2f;

    #pragma unroll
    for (int qq = 0; qq < 13; qq++) {
        double v = q[qq];
        #pragma unroll
        for (int off = 32; off > 0; off >>= 1) v += __shfl_down(v, off, 64);
        q[qq] = v;
    }

    __shared__ double red[2 * 13];
    const int lane = tid & 63, wid = tid >> 6;
    if (lane == 0) {
        #pragma unroll
        for (int qq = 0; qq < 13; qq++) red[wid * 13 + qq] = q[qq];
    }
    __syncthreads();
    if (tid < 13) {
        const double sfin = red[tid] + red[13 + tid];
        int idx;
        if      (tid < 4)  idx = b * KK + tid;              // Sm
        else if (tid < 8)  idx = 8  + b * KK + (tid - 4);   // Sim
        else if (tid < 12) idx = 16 + b * KK + (tid - 8);   // A
        else               idx = 24;                        // J2
        unsafeAtomicAdd(&ws[idx], sfin);
    }
}

__global__ void rfcm_fin(const double* __restrict__ ws, float* __restrict__ out)
{
    if (threadIdx.x == 0 && blockIdx.x == 0) {
        double j1 = 0;
        #pragma unroll
        for (int i = 0; i < BB * KK; i++)
            j1 += ws[16 + i] - ws[8 + i] * ws[8 + i] / ws[i];
        const double invBN = 1.0 / ((double)BB * (double)DD * (double)HH * (double)WW);
        out[0] = (float)(j1 * invBN + 0.0008 * ws[24] * invBN);
    }
}

extern "C" void kernel_launch(void* const* d_in, const int* in_sizes, int n_in,
                              void* d_out, int out_size, void* d_ws, size_t ws_size,
                              hipStream_t stream) {
    const float* yp  = (const float*)d_in[0];   // y_pred [2,4,128,128,128]
    const float* img = (const float*)d_in[1];   // image  [2,1,128,128,128]
    float* out = (float*)d_out;
    double* ws = (double*)d_ws;

    hipMemsetAsync(d_ws, 0, 25 * sizeof(double), stream);

    dim3 grid(BB * NBD * NBH);   // 2048 blocks
    rfcm_main<<<grid, NT, 0, stream>>>(yp, img, ws);
    rfcm_fin<<<1, 64, 0, stream>>>(ws, out);
}